// Round 10
// baseline (1330.114 us; speedup 1.0000x reference)
//
#include <hip/hip_runtime.h>

// GCLSDA encoder: ego=concat(U,I); 3x { ego = A@ego; ego += sign(ego)*nhat*0.1; acc+=ego }
// Outputs: final=acc/3, cl=ego_layer1.
// Numerics: SpMM accumulates per (row,dim) sequentially in ascending edge-index
// order with separate _rn mul/add (matches np.add.at); norm uses numpy
// pairwise-sum 8-accumulator pattern (fused in-wave since R9). Exact order is
// LOAD-BEARING: sign(ego) amplifies ~1e-7 reorder noise into ~1e-2 errors at
// near-zero ego elements. Do NOT reorder accumulation or the norm fold.
//
// R10: k_fused traffic surgery (252us x3 = 61% of total; FETCH 862MB = cv 51
// + nk 51 + ~760 x-gather fills at ~53% L2 hit).
//  (a) nt-hint single-use streams (cv, nk, mode2 clF read; all output
//      stores) — they churn 200MB/dispatch through the 4MB per-XCD L2 that
//      the x-gather needs (x rows reused ~4x/XCD). x loads stay cached.
//  (b) mode0 wrote ego(bufA) AND clF with identical bytes -> drop ego write;
//      LAYER 1 GATHERS FROM clF directly (-51MB write).
//  (c) mode1's accF=clF+e4 deferred to mode2: layer-1 e4 IS bufB (layer-2
//      x), so mode2 computes a=fadd(clF,bufB[idx]) — same association
//      ((cl+e1)+e2)/3, bit-identical — dropping mode1's clF read + accF
//      write (-102MB).
// R9 (verified): norm fused in-wave (7-step shfl_up ring, exact numpy
// order); per-block partial histograms (no memset/atomics); launches 11->7.
// R8 REVERTED (dim-split regressed: random gathers see per-XCD 4MB L2).
// R7: zip gather (one line/edge in k_build). R6: keys-only binning.
// R5: rank recomputed in k_bin phase 3. R3/R4: epilogue fused into spmm;
// layer-0 virtual concat; dead stores dropped.
//
// CSR build: bucket = row>>8 (782 buckets). A1 prep (partial counts + zip) ->
// scan -> A2 bin {key} -> B per-bucket rank-scatter (keys unique ((rl<<24)|e):
// final slot = start[rl] + #{same-row keys < mine}; each cv written ONCE).
// KEY RECOVERY MUST BE LOGICAL SHIFT: (unsigned)key>>24. e = key & 0xFFFFFF.
// Aliasing timeline: bcnt_part@CV (dead once scanned, before k_build writes
// cv); keys@bufA (build scratch only since R10); zip@bufB (dead before
// layer-1 ego write).

#define USER_NUM 100000
#define N_NODES  200000
#define EMB      64
#define N_EDGES  6400000
#define NBUCK    782        // ceil(200000/256)
#define CAP      9216       // max edges/bucket on LDS fast path (mu=8184, +11 sigma)
#define EPB      16384      // edges per block in A1/A2
#define TB_A     1024       // threads per block in A1/A2
#define NBLK     391        // ceil(N_EDGES/EPB)

static constexpr size_t BUFA_OFF  = 0;
static constexpr size_t BUFB_OFF  = 51200000;
static constexpr size_t CV_OFF    = 102400000;
static constexpr size_t RS_OFF    = 153600000;
static constexpr size_t SMALL_OFF = 154400016;
static constexpr size_t WS_NEED   = 156000016;

// ---- non-temporal (evict-first) load/store helpers ----
typedef float f4v __attribute__((ext_vector_type(4)));
typedef int   i2v __attribute__((ext_vector_type(2)));

__device__ __forceinline__ float4 ntload4(const float* p) {
    f4v v = __builtin_nontemporal_load((const f4v*)p);
    return make_float4(v.x, v.y, v.z, v.w);
}
__device__ __forceinline__ void ntstore4(float* p, float4 v) {
    f4v t = {v.x, v.y, v.z, v.w};
    __builtin_nontemporal_store(t, (f4v*)p);
}
__device__ __forceinline__ int2 ntload2(const int2* p) {
    i2v v = __builtin_nontemporal_load((const i2v*)p);
    return make_int2(v.x, v.y);
}

// ---- Pass A1: per-block bucket counts (no atomics/memset) + zip write ----
__global__ __launch_bounds__(TB_A) void k_prep(const int* __restrict__ rows,
                                               const int* __restrict__ cols,
                                               const float* __restrict__ vals,
                                               int* __restrict__ bcnt_part,
                                               int2* __restrict__ zip) {
    __shared__ int h[NBUCK];
    for (int i = threadIdx.x; i < NBUCK; i += TB_A) h[i] = 0;
    __syncthreads();
    int base = blockIdx.x * EPB;
    int end  = min(base + EPB, N_EDGES);
    for (int e = base + threadIdx.x; e < end; e += TB_A) {
        atomicAdd(&h[rows[e] >> 8], 1);
        zip[e] = make_int2(cols[e], __float_as_int(vals[e]));
    }
    __syncthreads();
    for (int i = threadIdx.x; i < NBUCK; i += TB_A)
        bcnt_part[blockIdx.x * NBUCK + i] = h[i];
}

// ---- sum partials + scan 782 -> bcnt, bbase (exclusive), gcur; rs[N]=E ----
__global__ void k_scan782(const int* __restrict__ bcnt_part,
                          int* __restrict__ bcnt, int* __restrict__ bbase,
                          int* __restrict__ gcur, int* __restrict__ rs) {
    __shared__ int s[1024];
    int i = threadIdx.x;
    int v = 0;
    if (i < NBUCK) {
        for (int b = 0; b < NBLK; ++b) v += bcnt_part[b * NBUCK + i];
        bcnt[i] = v;
    }
    s[i] = v;
    __syncthreads();
    for (int off = 1; off < 1024; off <<= 1) {
        int t = 0;
        if (i >= off) t = s[i - off];
        __syncthreads();
        s[i] += t;
        __syncthreads();
    }
    if (i < NBUCK) {
        int ex = s[i] - v;
        bbase[i] = ex;
        gcur[i] = ex;
    }
    if (i == 0) rs[N_NODES] = N_EDGES;
}

// ---- Pass A2: bin edge KEYS into bucket regions (keys only). Phase 1: LDS
// histogram. Phase 2: one global reservation per non-empty bucket. Phase 3:
// re-read rows (L2-hot), recompute rank via fresh LDS atomicAdd —
// intra-bucket order is arbitrary (k_build sorts by key). ----
__global__ __launch_bounds__(TB_A) void k_bin(const int* __restrict__ rows,
                                              int* __restrict__ gcur,
                                              int* __restrict__ keys) {
    __shared__ int h[NBUCK];
    __shared__ int gb[NBUCK];
    for (int i = threadIdx.x; i < NBUCK; i += TB_A) h[i] = 0;
    __syncthreads();
    int base = blockIdx.x * EPB;
    int end  = min(base + EPB, N_EDGES);
    for (int e = base + threadIdx.x; e < end; e += TB_A)
        atomicAdd(&h[rows[e] >> 8], 1);
    __syncthreads();
    for (int i = threadIdx.x; i < NBUCK; i += TB_A) {
        int c = h[i];
        gb[i] = c ? atomicAdd(&gcur[i], c) : 0;
        h[i] = 0;
    }
    __syncthreads();
    for (int e = base + threadIdx.x; e < end; e += TB_A) {
        int r = rows[e];
        int b = r >> 8;
        int pos = gb[b] + atomicAdd(&h[b], 1);
        keys[pos] = ((r & 255) << 24) | e;  // e < 2^23, row-local in top byte
    }
}

// ---- Pass B: per-bucket row-grouping + stable (edge-idx) ordering -> cv, rs.
// (col,val) gathered from zip via e = key & 0xFFFFFF: ONE 64B line per edge. ----
__global__ __launch_bounds__(256) void k_build(const int* __restrict__ keys,
                                               const int2* __restrict__ zip,
                                               const int* __restrict__ bcnt,
                                               const int* __restrict__ bbase,
                                               int2* __restrict__ cv,
                                               int* __restrict__ rs) {
    __shared__ int cnt[256];
    __shared__ int start[256];
    __shared__ int cur[256];
    __shared__ int scanbuf[256];
    __shared__ int eKey[CAP];     // grouped keys (fast path)
    int tid = threadIdx.x;
    int b = blockIdx.x;
    int n = bcnt[b];
    int base = bbase[b];
    int rowbase = b << 8;
    cnt[tid] = 0;
    __syncthreads();
    // step 1: per-row-local histogram (LOGICAL shift: rl in [0,255])
    for (int i = tid; i < n; i += 256) {
        unsigned key = (unsigned)keys[base + i];
        atomicAdd(&cnt[key >> 24], 1);
    }
    __syncthreads();
    // exclusive scan of cnt -> start
    int v = cnt[tid];
    scanbuf[tid] = v;
    __syncthreads();
    for (int off = 1; off < 256; off <<= 1) {
        int t = 0;
        if (tid >= off) t = scanbuf[tid - off];
        __syncthreads();
        scanbuf[tid] += t;
        __syncthreads();
    }
    start[tid] = scanbuf[tid] - v;
    {
        int row = rowbase + tid;
        if (row < N_NODES) rs[row] = base + start[tid];
    }
    cur[tid] = 0;
    __syncthreads();
    if (n <= CAP) {
        // step 2: group keys by row into LDS (intra-row order arbitrary here)
        for (int i = tid; i < n; i += 256) {
            int key = keys[base + i];                   // L2-hot re-read
            int rl = (int)((unsigned)key >> 24);
            int p = start[rl] + atomicAdd(&cur[rl], 1);
            eKey[p] = key;
        }
        __syncthreads();
        // step 3: rank = #{same-row keys < mine} -> final slot; write cv ONCE.
        // Keys unique => bijection; same top byte within a row => signed cmp
        // orders by edge idx. (col,val) gathered from zip in one line.
        for (int p = tid; p < n; p += 256) {
            int k = eKey[p];
            int rl = (int)((unsigned)k >> 24);
            int s0 = start[rl];
            int s1 = s0 + cnt[rl];
            int rank = 0;
            int q = s0;
            for (; q + 4 <= s1; q += 4) {
                rank += (eKey[q]     < k);
                rank += (eKey[q + 1] < k);
                rank += (eKey[q + 2] < k);
                rank += (eKey[q + 3] < k);
            }
            for (; q < s1; ++q) rank += (eKey[q] < k);
            int e = k & 0x00FFFFFF;
            cv[base + s0 + rank] = zip[e];
        }
    } else {
        // overflow fallback (statistically unreachable, +11 sigma):
        // scatter keys into cv[].x, per-row insertion sort by key (global,
        // slow but correct), then rewrite each slot from zip via e.
        for (int i = tid; i < n; i += 256) {
            int key = keys[base + i];
            int rl = (int)((unsigned)key >> 24);
            int p = start[rl] + atomicAdd(&cur[rl], 1);
            cv[base + p] = make_int2(key, 0);
        }
        __syncthreads();
        int c = cnt[tid];
        if (c > 1) {
            int s0 = start[tid];
            int s1 = s0 + c;
            for (int i = s0 + 1; i < s1; ++i) {
                int2 kv = cv[base + i];
                int j = i - 1;
                while (j >= s0 && cv[base + j].x > kv.x) {
                    cv[base + j + 1] = cv[base + j];
                    --j;
                }
                cv[base + j + 1] = kv;
            }
        }
        __syncthreads();
        // each slot read exactly once by its own thread, then overwritten
        for (int i = tid; i < n; i += 256) {
            int e = cv[base + i].x & 0x00FFFFFF;
            cv[base + i] = zip[e];
        }
    }
}

// ---- Fused SpMM + norm + epilogue. One thread per (row, 4-dim group); a
// row's 16 threads form one 16-lane wave segment. Row norm computed in-wave
// (exact numpy pairwise order): lane u holds dims 4u..4u+3; chains rj[0..3]
// are left-folds over even lanes, rj[4..7] over odd lanes, both in increasing
// lane order -> 7-step serial __shfl_up(.,2,16) ring; lane14 ends with
// r0..r3, lane15 with r4..r7; tAB = fadd(fadd(f0,f1),fadd(f2,f3)) gives
// s01+s23 (lane14) and s45+s67 (lane15); ss = fadd(lane14,lane15).
// 3-edge pipelined gather groups. x gather (CACHED loads) selects {base,
// rebased col} in-kernel: layer 0 reads user/item directly (split=100000);
// layer 1 gathers from clF; layer 2 from bufB. cv/nk are nt (single-use).
// Epilogue: e4 = y + sign(y)*nk/nv*0.1;
//   mode0: clF=e4                    (ego dropped — layer 1 reads clF)
//   mode1: ego=e4                    (acc deferred — e4 IS layer-2's x)
//   mode2: a=fadd(clF,x[idx]); accF=fdiv(fadd(a,e4),3)
//     (a == old mode1's accF=clF+e4_l1 bit-exactly: x[idx]=bufB[idx]=e4_l1)
// NOTE: grid exactly covers N_NODES*16 threads — no lane early-exits, so the
// shfl ring sees all 16 lanes of every segment.
__global__ __launch_bounds__(256) void k_fused(const int* __restrict__ rs,
                                               const int2* __restrict__ cv,
                                               const float* __restrict__ xlo,
                                               const float* __restrict__ xhi,
                                               int split,
                                               const float* __restrict__ nk,
                                               float* __restrict__ ego,
                                               float* __restrict__ accF,
                                               float* __restrict__ clF,
                                               int mode) {
    int t = blockIdx.x * blockDim.x + threadIdx.x;
    int r = t >> 4;
    int u = t & 15;
    int c = u << 2;
    int idx = t << 2;                       // == r*EMB + c
    // ---- in-wave row norm (exact numpy pairwise order) ----
    float4 n4 = ntload4(nk + idx);
    float q0 = __fmul_rn(n4.x, n4.x);
    float q1 = __fmul_rn(n4.y, n4.y);
    float q2 = __fmul_rn(n4.z, n4.z);
    float q3 = __fmul_rn(n4.w, n4.w);
    float f0 = q0, f1 = q1, f2 = q2, f3 = q3;
    #pragma unroll
    for (int s = 0; s < 7; ++s) {
        float g0 = __shfl_up(f0, 2, 16);
        float g1 = __shfl_up(f1, 2, 16);
        float g2 = __shfl_up(f2, 2, 16);
        float g3 = __shfl_up(f3, 2, 16);
        if (u >= 2) {
            f0 = __fadd_rn(g0, q0);
            f1 = __fadd_rn(g1, q1);
            f2 = __fadd_rn(g2, q2);
            f3 = __fadd_rn(g3, q3);
        }
    }
    float tAB = __fadd_rn(__fadd_rn(f0, f1), __fadd_rn(f2, f3));
    float tlo = __shfl(tAB, 14, 16);        // s01+s23 (chains from even lanes)
    float thi = __shfl(tAB, 15, 16);        // s45+s67 (chains from odd lanes)
    float nv = __fsqrt_rn(__fadd_rn(tlo, thi));
    nv = fmaxf(nv, 1e-12f);
    // ---- SpMM ----
    int j0 = rs[r], j1 = rs[r + 1];
    float a0 = 0.f, a1 = 0.f, a2 = 0.f, a3 = 0.f;
    if (j0 < j1) {
        const int EMAX = N_EDGES - 1;
        // two-base gather: base and rebased column selected together
        #define XROW(col) (((col) < split ? xlo : xhi) + \
                           ((col) < split ? (col) : (col) - split) * EMB + c)
        int2 c0 = ntload2(&cv[j0]);
        int2 c1 = ntload2(&cv[min(j0 + 1, EMAX)]);
        int2 c2 = ntload2(&cv[min(j0 + 2, EMAX)]);
        int2 n0 = ntload2(&cv[min(j0 + 3, EMAX)]);
        int2 n1 = ntload2(&cv[min(j0 + 4, EMAX)]);
        int2 n2 = ntload2(&cv[min(j0 + 5, EMAX)]);
        int2 m0 = ntload2(&cv[min(j0 + 6, EMAX)]);
        int2 m1 = ntload2(&cv[min(j0 + 7, EMAX)]);
        int2 m2 = ntload2(&cv[min(j0 + 8, EMAX)]);
        float4 x0 = *(const float4*)XROW(c0.x);
        float4 x1 = *(const float4*)XROW(c1.x);
        float4 x2 = *(const float4*)XROW(c2.x);
        for (int j = j0; j < j1; j += 3) {
            // x prefetch for next group (cv loaded 2 iterations ago)
            float4 y0 = *(const float4*)XROW(n0.x);
            float4 y1 = *(const float4*)XROW(n1.x);
            float4 y2 = *(const float4*)XROW(n2.x);
            // accumulate current group (predicate out-of-row edges to v=0;
            // a + (+/-0) is exact, so active-edge order/values unchanged)
            float v0 = __int_as_float(c0.y);
            float v1 = (j + 1 < j1) ? __int_as_float(c1.y) : 0.f;
            float v2 = (j + 2 < j1) ? __int_as_float(c2.y) : 0.f;
            a0 = __fadd_rn(a0, __fmul_rn(v0, x0.x));
            a1 = __fadd_rn(a1, __fmul_rn(v0, x0.y));
            a2 = __fadd_rn(a2, __fmul_rn(v0, x0.z));
            a3 = __fadd_rn(a3, __fmul_rn(v0, x0.w));
            a0 = __fadd_rn(a0, __fmul_rn(v1, x1.x));
            a1 = __fadd_rn(a1, __fmul_rn(v1, x1.y));
            a2 = __fadd_rn(a2, __fmul_rn(v1, x1.z));
            a3 = __fadd_rn(a3, __fmul_rn(v1, x1.w));
            a0 = __fadd_rn(a0, __fmul_rn(v2, x2.x));
            a1 = __fadd_rn(a1, __fmul_rn(v2, x2.y));
            a2 = __fadd_rn(a2, __fmul_rn(v2, x2.z));
            a3 = __fadd_rn(a3, __fmul_rn(v2, x2.w));
            // rotate pipeline
            c0 = n0; c1 = n1; c2 = n2;
            n0 = m0; n1 = m1; n2 = m2;
            x0 = y0; x1 = y1; x2 = y2;
            // streaming cv prefetch, 2 groups ahead of its x-gather
            m0 = ntload2(&cv[min(j + 9,  EMAX)]);
            m1 = ntload2(&cv[min(j + 10, EMAX)]);
            m2 = ntload2(&cv[min(j + 11, EMAX)]);
        }
        #undef XROW
    }
    // ---- fused epilogue (identical math/order to the original k_epi) ----
    float4 e4;
    {
        float s, q;
        s = (a0 > 0.f) ? 1.f : ((a0 < 0.f) ? -1.f : 0.f);
        q = __fdiv_rn(n4.x, nv);
        e4.x = __fadd_rn(a0, __fmul_rn(__fmul_rn(s, q), 0.1f));
        s = (a1 > 0.f) ? 1.f : ((a1 < 0.f) ? -1.f : 0.f);
        q = __fdiv_rn(n4.y, nv);
        e4.y = __fadd_rn(a1, __fmul_rn(__fmul_rn(s, q), 0.1f));
        s = (a2 > 0.f) ? 1.f : ((a2 < 0.f) ? -1.f : 0.f);
        q = __fdiv_rn(n4.z, nv);
        e4.z = __fadd_rn(a2, __fmul_rn(__fmul_rn(s, q), 0.1f));
        s = (a3 > 0.f) ? 1.f : ((a3 < 0.f) ? -1.f : 0.f);
        q = __fdiv_rn(n4.w, nv);
        e4.w = __fadd_rn(a3, __fmul_rn(__fmul_rn(s, q), 0.1f));
    }
    if (mode == 0) {
        ntstore4(clF + idx, e4);
    } else if (mode == 1) {
        ntstore4(ego + idx, e4);
    } else {
        float4 cl4 = ntload4(clF + idx);
        float4 x1 = *(const float4*)(xhi + idx);  // bufB = layer-1 e4 (cached:
        float4 a;                                 // it's this layer's x too)
        a.x = __fadd_rn(cl4.x, x1.x);
        a.y = __fadd_rn(cl4.y, x1.y);
        a.z = __fadd_rn(cl4.z, x1.z);
        a.w = __fadd_rn(cl4.w, x1.w);
        float4 f;
        f.x = __fdiv_rn(__fadd_rn(a.x, e4.x), 3.0f);
        f.y = __fdiv_rn(__fadd_rn(a.y, e4.y), 3.0f);
        f.z = __fdiv_rn(__fadd_rn(a.z, e4.z), 3.0f);
        f.w = __fdiv_rn(__fadd_rn(a.w, e4.w), 3.0f);
        ntstore4(accF + idx, f);
    }
}

extern "C" void kernel_launch(void* const* d_in, const int* in_sizes, int n_in,
                              void* d_out, int out_size, void* d_ws, size_t ws_size,
                              hipStream_t stream) {
    if (ws_size < WS_NEED) return;

    const float* user_emb = (const float*)d_in[0];
    const float* item_emb = (const float*)d_in[1];
    const int*   adj_rows = (const int*)d_in[2];
    const int*   adj_cols = (const int*)d_in[3];
    const float* adj_vals = (const float*)d_in[4];
    const float* noise    = (const float*)d_in[5];

    char* ws = (char*)d_ws;
    float* bufB = (float*)(ws + BUFB_OFF);
    int*   keys = (int*)(ws + BUFA_OFF);    // build scratch (bufA unused since R10)
    int2*  zip  = (int2*)(ws + BUFB_OFF);   // aliased: dead before bufB first write
    int*   bcnt_part = (int*)(ws + CV_OFF); // aliased: dead before cv written
    int2*  cv   = (int2*)(ws + CV_OFF);
    int*   rs   = (int*)(ws + RS_OFF);
    int*   bcnt = (int*)(ws + SMALL_OFF);
    int*   bbase= (int*)(ws + SMALL_OFF + 3200);
    int*   gcur = (int*)(ws + SMALL_OFF + 6400);

    float* accF = (float*)d_out;
    float* clF  = (float*)d_out + (size_t)N_NODES * EMB;

    // ---- CSR build (keys/zip/bcnt_part alias ws regions: all consumed
    //      before their aliases are written; single stream) ----
    k_prep<<<NBLK, TB_A, 0, stream>>>(adj_rows, adj_cols, adj_vals, bcnt_part,
                                      zip);
    k_scan782<<<1, 1024, 0, stream>>>(bcnt_part, bcnt, bbase, gcur, rs);
    k_bin<<<NBLK, TB_A, 0, stream>>>(adj_rows, gcur, keys);
    k_build<<<NBUCK, 256, 0, stream>>>(keys, zip, bcnt, bbase, cv, rs);

    // ---- 3 layers: fused norm+spmm+epilogue ----
    // L0: gather user/item -> write clF. L1: gather clF -> write bufB.
    // L2: gather bufB -> write accF (acc recomputed from clF + bufB).
    const int T16 = N_NODES * 16;
    for (int k = 0; k < 3; ++k) {
        const float* nkp = noise + (size_t)k * N_NODES * EMB;
        const float* xlo  = (k == 0) ? user_emb : ((k == 1) ? clF : bufB);
        const float* xhi  = (k == 0) ? item_emb : ((k == 1) ? clF : bufB);
        int split = (k == 0) ? USER_NUM : 0;
        k_fused<<<T16 / 256, 256, 0, stream>>>(rs, cv, xlo, xhi, split,
                                               nkp, bufB, accF, clF, k);
    }
}

// Round 11
// 1210.455 us; speedup vs baseline: 1.0989x; 1.0989x over previous
//
#include <hip/hip_runtime.h>

// GCLSDA encoder: ego=concat(U,I); 3x { ego = A@ego; ego += sign(ego)*nhat*0.1; acc+=ego }
// Outputs: final=acc/3, cl=ego_layer1.
// Numerics: SpMM accumulates per (row,dim) sequentially in ascending edge-index
// order with separate _rn mul/add (matches np.add.at); norm uses numpy
// pairwise-sum 8-accumulator pattern (fused in-wave since R9). Exact order is
// LOAD-BEARING: sign(ego) amplifies ~1e-7 reorder noise into ~1e-2 errors at
// near-zero ego elements. Do NOT reorder accumulation or the norm fold.
//
// R11: revert nt on CV LOADS only. R10 post-mortem: FETCH rose 862->1015MB
// (+153MB ~= 3x cv stream) — cv lines have short-range reuse (8 entries/64B
// line, walked across ~3 successive 3-edge iterations); nt (no-allocate)
// re-fetched each touch. nk/stores are genuinely single-touch -> keep nt
// there (L2 depollution for the x-gather). R10's dataflow deletions KEPT:
//  (b) mode0 single store (layer 1 gathers from clF, -51MB write)
//  (c) acc deferred to mode2: a=fadd(clF,bufB[idx]) == ((cl+e1)+e2), bit-
//      identical, -102MB (mode1 clF read + accF write).
// R9 (verified): norm fused in-wave (7-step shfl_up ring, exact numpy
// order); per-block partial histograms; launches 11->7.
// R8 REVERTED (dim-split: random gathers see per-XCD 4MB L2, split didn't
// cut misses). R7: zip gather. R6: keys-only binning. R5: rank recomputed in
// k_bin phase 3. R3/R4: epilogue fused into spmm; layer-0 virtual concat.
//
// CSR build: bucket = row>>8 (782 buckets). A1 prep (partial counts + zip) ->
// scan -> A2 bin {key} -> B per-bucket rank-scatter (keys unique ((rl<<24)|e):
// final slot = start[rl] + #{same-row keys < mine}; each cv written ONCE).
// KEY RECOVERY MUST BE LOGICAL SHIFT: (unsigned)key>>24. e = key & 0xFFFFFF.
// Aliasing timeline: bcnt_part@CV (dead once scanned, before k_build writes
// cv); keys@bufA (build scratch only); zip@bufB (dead before layer-1 write).

#define USER_NUM 100000
#define N_NODES  200000
#define EMB      64
#define N_EDGES  6400000
#define NBUCK    782        // ceil(200000/256)
#define CAP      9216       // max edges/bucket on LDS fast path (mu=8184, +11 sigma)
#define EPB      16384      // edges per block in A1/A2
#define TB_A     1024       // threads per block in A1/A2
#define NBLK     391        // ceil(N_EDGES/EPB)

static constexpr size_t BUFA_OFF  = 0;
static constexpr size_t BUFB_OFF  = 51200000;
static constexpr size_t CV_OFF    = 102400000;
static constexpr size_t RS_OFF    = 153600000;
static constexpr size_t SMALL_OFF = 154400016;
static constexpr size_t WS_NEED   = 156000016;

// ---- non-temporal (evict-first) load/store helpers — SINGLE-TOUCH streams
// only (nk, mode2 clF read, output stores). NOT cv (line reuse, R10 lesson).
typedef float f4v __attribute__((ext_vector_type(4)));

__device__ __forceinline__ float4 ntload4(const float* p) {
    f4v v = __builtin_nontemporal_load((const f4v*)p);
    return make_float4(v.x, v.y, v.z, v.w);
}
__device__ __forceinline__ void ntstore4(float* p, float4 v) {
    f4v t = {v.x, v.y, v.z, v.w};
    __builtin_nontemporal_store(t, (f4v*)p);
}

// ---- Pass A1: per-block bucket counts (no atomics/memset) + zip write ----
__global__ __launch_bounds__(TB_A) void k_prep(const int* __restrict__ rows,
                                               const int* __restrict__ cols,
                                               const float* __restrict__ vals,
                                               int* __restrict__ bcnt_part,
                                               int2* __restrict__ zip) {
    __shared__ int h[NBUCK];
    for (int i = threadIdx.x; i < NBUCK; i += TB_A) h[i] = 0;
    __syncthreads();
    int base = blockIdx.x * EPB;
    int end  = min(base + EPB, N_EDGES);
    for (int e = base + threadIdx.x; e < end; e += TB_A) {
        atomicAdd(&h[rows[e] >> 8], 1);
        zip[e] = make_int2(cols[e], __float_as_int(vals[e]));
    }
    __syncthreads();
    for (int i = threadIdx.x; i < NBUCK; i += TB_A)
        bcnt_part[blockIdx.x * NBUCK + i] = h[i];
}

// ---- sum partials + scan 782 -> bcnt, bbase (exclusive), gcur; rs[N]=E ----
__global__ void k_scan782(const int* __restrict__ bcnt_part,
                          int* __restrict__ bcnt, int* __restrict__ bbase,
                          int* __restrict__ gcur, int* __restrict__ rs) {
    __shared__ int s[1024];
    int i = threadIdx.x;
    int v = 0;
    if (i < NBUCK) {
        for (int b = 0; b < NBLK; ++b) v += bcnt_part[b * NBUCK + i];
        bcnt[i] = v;
    }
    s[i] = v;
    __syncthreads();
    for (int off = 1; off < 1024; off <<= 1) {
        int t = 0;
        if (i >= off) t = s[i - off];
        __syncthreads();
        s[i] += t;
        __syncthreads();
    }
    if (i < NBUCK) {
        int ex = s[i] - v;
        bbase[i] = ex;
        gcur[i] = ex;
    }
    if (i == 0) rs[N_NODES] = N_EDGES;
}

// ---- Pass A2: bin edge KEYS into bucket regions (keys only). Phase 1: LDS
// histogram. Phase 2: one global reservation per non-empty bucket. Phase 3:
// re-read rows (L2-hot), recompute rank via fresh LDS atomicAdd —
// intra-bucket order is arbitrary (k_build sorts by key). ----
__global__ __launch_bounds__(TB_A) void k_bin(const int* __restrict__ rows,
                                              int* __restrict__ gcur,
                                              int* __restrict__ keys) {
    __shared__ int h[NBUCK];
    __shared__ int gb[NBUCK];
    for (int i = threadIdx.x; i < NBUCK; i += TB_A) h[i] = 0;
    __syncthreads();
    int base = blockIdx.x * EPB;
    int end  = min(base + EPB, N_EDGES);
    for (int e = base + threadIdx.x; e < end; e += TB_A)
        atomicAdd(&h[rows[e] >> 8], 1);
    __syncthreads();
    for (int i = threadIdx.x; i < NBUCK; i += TB_A) {
        int c = h[i];
        gb[i] = c ? atomicAdd(&gcur[i], c) : 0;
        h[i] = 0;
    }
    __syncthreads();
    for (int e = base + threadIdx.x; e < end; e += TB_A) {
        int r = rows[e];
        int b = r >> 8;
        int pos = gb[b] + atomicAdd(&h[b], 1);
        keys[pos] = ((r & 255) << 24) | e;  // e < 2^23, row-local in top byte
    }
}

// ---- Pass B: per-bucket row-grouping + stable (edge-idx) ordering -> cv, rs.
// (col,val) gathered from zip via e = key & 0xFFFFFF: ONE 64B line per edge. ----
__global__ __launch_bounds__(256) void k_build(const int* __restrict__ keys,
                                               const int2* __restrict__ zip,
                                               const int* __restrict__ bcnt,
                                               const int* __restrict__ bbase,
                                               int2* __restrict__ cv,
                                               int* __restrict__ rs) {
    __shared__ int cnt[256];
    __shared__ int start[256];
    __shared__ int cur[256];
    __shared__ int scanbuf[256];
    __shared__ int eKey[CAP];     // grouped keys (fast path)
    int tid = threadIdx.x;
    int b = blockIdx.x;
    int n = bcnt[b];
    int base = bbase[b];
    int rowbase = b << 8;
    cnt[tid] = 0;
    __syncthreads();
    // step 1: per-row-local histogram (LOGICAL shift: rl in [0,255])
    for (int i = tid; i < n; i += 256) {
        unsigned key = (unsigned)keys[base + i];
        atomicAdd(&cnt[key >> 24], 1);
    }
    __syncthreads();
    // exclusive scan of cnt -> start
    int v = cnt[tid];
    scanbuf[tid] = v;
    __syncthreads();
    for (int off = 1; off < 256; off <<= 1) {
        int t = 0;
        if (tid >= off) t = scanbuf[tid - off];
        __syncthreads();
        scanbuf[tid] += t;
        __syncthreads();
    }
    start[tid] = scanbuf[tid] - v;
    {
        int row = rowbase + tid;
        if (row < N_NODES) rs[row] = base + start[tid];
    }
    cur[tid] = 0;
    __syncthreads();
    if (n <= CAP) {
        // step 2: group keys by row into LDS (intra-row order arbitrary here)
        for (int i = tid; i < n; i += 256) {
            int key = keys[base + i];                   // L2-hot re-read
            int rl = (int)((unsigned)key >> 24);
            int p = start[rl] + atomicAdd(&cur[rl], 1);
            eKey[p] = key;
        }
        __syncthreads();
        // step 3: rank = #{same-row keys < mine} -> final slot; write cv ONCE.
        // Keys unique => bijection; same top byte within a row => signed cmp
        // orders by edge idx. (col,val) gathered from zip in one line.
        for (int p = tid; p < n; p += 256) {
            int k = eKey[p];
            int rl = (int)((unsigned)k >> 24);
            int s0 = start[rl];
            int s1 = s0 + cnt[rl];
            int rank = 0;
            int q = s0;
            for (; q + 4 <= s1; q += 4) {
                rank += (eKey[q]     < k);
                rank += (eKey[q + 1] < k);
                rank += (eKey[q + 2] < k);
                rank += (eKey[q + 3] < k);
            }
            for (; q < s1; ++q) rank += (eKey[q] < k);
            int e = k & 0x00FFFFFF;
            cv[base + s0 + rank] = zip[e];
        }
    } else {
        // overflow fallback (statistically unreachable, +11 sigma):
        // scatter keys into cv[].x, per-row insertion sort by key (global,
        // slow but correct), then rewrite each slot from zip via e.
        for (int i = tid; i < n; i += 256) {
            int key = keys[base + i];
            int rl = (int)((unsigned)key >> 24);
            int p = start[rl] + atomicAdd(&cur[rl], 1);
            cv[base + p] = make_int2(key, 0);
        }
        __syncthreads();
        int c = cnt[tid];
        if (c > 1) {
            int s0 = start[tid];
            int s1 = s0 + c;
            for (int i = s0 + 1; i < s1; ++i) {
                int2 kv = cv[base + i];
                int j = i - 1;
                while (j >= s0 && cv[base + j].x > kv.x) {
                    cv[base + j + 1] = cv[base + j];
                    --j;
                }
                cv[base + j + 1] = kv;
            }
        }
        __syncthreads();
        // each slot read exactly once by its own thread, then overwritten
        for (int i = tid; i < n; i += 256) {
            int e = cv[base + i].x & 0x00FFFFFF;
            cv[base + i] = zip[e];
        }
    }
}

// ---- Fused SpMM + norm + epilogue. One thread per (row, 4-dim group); a
// row's 16 threads form one 16-lane wave segment. Row norm computed in-wave
// (exact numpy pairwise order): lane u holds dims 4u..4u+3; chains rj[0..3]
// are left-folds over even lanes, rj[4..7] over odd lanes, both in increasing
// lane order -> 7-step serial __shfl_up(.,2,16) ring; lane14 ends with
// r0..r3, lane15 with r4..r7; tAB = fadd(fadd(f0,f1),fadd(f2,f3)) gives
// s01+s23 (lane14) and s45+s67 (lane15); ss = fadd(lane14,lane15).
// 3-edge pipelined gather groups. x gather AND cv loads are CACHED (cv has
// line reuse — R10 lesson); nk is nt (single-touch). x base select {base,
// rebased col} in-kernel: layer 0 reads user/item directly (split=100000);
// layer 1 gathers from clF; layer 2 from bufB.
// Epilogue: e4 = y + sign(y)*nk/nv*0.1;
//   mode0: clF=e4                    (ego dropped — layer 1 reads clF)
//   mode1: ego=e4                    (acc deferred — e4 IS layer-2's x)
//   mode2: a=fadd(clF,x[idx]); accF=fdiv(fadd(a,e4),3)
//     (a == old mode1's accF=clF+e4_l1 bit-exactly: x[idx]=bufB[idx]=e4_l1)
// NOTE: grid exactly covers N_NODES*16 threads — no lane early-exits, so the
// shfl ring sees all 16 lanes of every segment.
__global__ __launch_bounds__(256) void k_fused(const int* __restrict__ rs,
                                               const int2* __restrict__ cv,
                                               const float* __restrict__ xlo,
                                               const float* __restrict__ xhi,
                                               int split,
                                               const float* __restrict__ nk,
                                               float* __restrict__ ego,
                                               float* __restrict__ accF,
                                               float* __restrict__ clF,
                                               int mode) {
    int t = blockIdx.x * blockDim.x + threadIdx.x;
    int r = t >> 4;
    int u = t & 15;
    int c = u << 2;
    int idx = t << 2;                       // == r*EMB + c
    // ---- in-wave row norm (exact numpy pairwise order) ----
    float4 n4 = ntload4(nk + idx);
    float q0 = __fmul_rn(n4.x, n4.x);
    float q1 = __fmul_rn(n4.y, n4.y);
    float q2 = __fmul_rn(n4.z, n4.z);
    float q3 = __fmul_rn(n4.w, n4.w);
    float f0 = q0, f1 = q1, f2 = q2, f3 = q3;
    #pragma unroll
    for (int s = 0; s < 7; ++s) {
        float g0 = __shfl_up(f0, 2, 16);
        float g1 = __shfl_up(f1, 2, 16);
        float g2 = __shfl_up(f2, 2, 16);
        float g3 = __shfl_up(f3, 2, 16);
        if (u >= 2) {
            f0 = __fadd_rn(g0, q0);
            f1 = __fadd_rn(g1, q1);
            f2 = __fadd_rn(g2, q2);
            f3 = __fadd_rn(g3, q3);
        }
    }
    float tAB = __fadd_rn(__fadd_rn(f0, f1), __fadd_rn(f2, f3));
    float tlo = __shfl(tAB, 14, 16);        // s01+s23 (chains from even lanes)
    float thi = __shfl(tAB, 15, 16);        // s45+s67 (chains from odd lanes)
    float nv = __fsqrt_rn(__fadd_rn(tlo, thi));
    nv = fmaxf(nv, 1e-12f);
    // ---- SpMM ----
    int j0 = rs[r], j1 = rs[r + 1];
    float a0 = 0.f, a1 = 0.f, a2 = 0.f, a3 = 0.f;
    if (j0 < j1) {
        const int EMAX = N_EDGES - 1;
        // two-base gather: base and rebased column selected together
        #define XROW(col) (((col) < split ? xlo : xhi) + \
                           ((col) < split ? (col) : (col) - split) * EMB + c)
        int2 c0 = cv[j0];
        int2 c1 = cv[min(j0 + 1, EMAX)];
        int2 c2 = cv[min(j0 + 2, EMAX)];
        int2 n0 = cv[min(j0 + 3, EMAX)];
        int2 n1 = cv[min(j0 + 4, EMAX)];
        int2 n2 = cv[min(j0 + 5, EMAX)];
        int2 m0 = cv[min(j0 + 6, EMAX)];
        int2 m1 = cv[min(j0 + 7, EMAX)];
        int2 m2 = cv[min(j0 + 8, EMAX)];
        float4 x0 = *(const float4*)XROW(c0.x);
        float4 x1 = *(const float4*)XROW(c1.x);
        float4 x2 = *(const float4*)XROW(c2.x);
        for (int j = j0; j < j1; j += 3) {
            // x prefetch for next group (cv loaded 2 iterations ago)
            float4 y0 = *(const float4*)XROW(n0.x);
            float4 y1 = *(const float4*)XROW(n1.x);
            float4 y2 = *(const float4*)XROW(n2.x);
            // accumulate current group (predicate out-of-row edges to v=0;
            // a + (+/-0) is exact, so active-edge order/values unchanged)
            float v0 = __int_as_float(c0.y);
            float v1 = (j + 1 < j1) ? __int_as_float(c1.y) : 0.f;
            float v2 = (j + 2 < j1) ? __int_as_float(c2.y) : 0.f;
            a0 = __fadd_rn(a0, __fmul_rn(v0, x0.x));
            a1 = __fadd_rn(a1, __fmul_rn(v0, x0.y));
            a2 = __fadd_rn(a2, __fmul_rn(v0, x0.z));
            a3 = __fadd_rn(a3, __fmul_rn(v0, x0.w));
            a0 = __fadd_rn(a0, __fmul_rn(v1, x1.x));
            a1 = __fadd_rn(a1, __fmul_rn(v1, x1.y));
            a2 = __fadd_rn(a2, __fmul_rn(v1, x1.z));
            a3 = __fadd_rn(a3, __fmul_rn(v1, x1.w));
            a0 = __fadd_rn(a0, __fmul_rn(v2, x2.x));
            a1 = __fadd_rn(a1, __fmul_rn(v2, x2.y));
            a2 = __fadd_rn(a2, __fmul_rn(v2, x2.z));
            a3 = __fadd_rn(a3, __fmul_rn(v2, x2.w));
            // rotate pipeline
            c0 = n0; c1 = n1; c2 = n2;
            n0 = m0; n1 = m1; n2 = m2;
            x0 = y0; x1 = y1; x2 = y2;
            // streaming cv prefetch, 2 groups ahead of its x-gather
            m0 = cv[min(j + 9,  EMAX)];
            m1 = cv[min(j + 10, EMAX)];
            m2 = cv[min(j + 11, EMAX)];
        }
        #undef XROW
    }
    // ---- fused epilogue (identical math/order to the original k_epi) ----
    float4 e4;
    {
        float s, q;
        s = (a0 > 0.f) ? 1.f : ((a0 < 0.f) ? -1.f : 0.f);
        q = __fdiv_rn(n4.x, nv);
        e4.x = __fadd_rn(a0, __fmul_rn(__fmul_rn(s, q), 0.1f));
        s = (a1 > 0.f) ? 1.f : ((a1 < 0.f) ? -1.f : 0.f);
        q = __fdiv_rn(n4.y, nv);
        e4.y = __fadd_rn(a1, __fmul_rn(__fmul_rn(s, q), 0.1f));
        s = (a2 > 0.f) ? 1.f : ((a2 < 0.f) ? -1.f : 0.f);
        q = __fdiv_rn(n4.z, nv);
        e4.z = __fadd_rn(a2, __fmul_rn(__fmul_rn(s, q), 0.1f));
        s = (a3 > 0.f) ? 1.f : ((a3 < 0.f) ? -1.f : 0.f);
        q = __fdiv_rn(n4.w, nv);
        e4.w = __fadd_rn(a3, __fmul_rn(__fmul_rn(s, q), 0.1f));
    }
    if (mode == 0) {
        ntstore4(clF + idx, e4);
    } else if (mode == 1) {
        ntstore4(ego + idx, e4);
    } else {
        float4 cl4 = ntload4(clF + idx);
        float4 x1 = *(const float4*)(xhi + idx);  // bufB = layer-1 e4 (cached:
        float4 a;                                 // it's this layer's x too)
        a.x = __fadd_rn(cl4.x, x1.x);
        a.y = __fadd_rn(cl4.y, x1.y);
        a.z = __fadd_rn(cl4.z, x1.z);
        a.w = __fadd_rn(cl4.w, x1.w);
        float4 f;
        f.x = __fdiv_rn(__fadd_rn(a.x, e4.x), 3.0f);
        f.y = __fdiv_rn(__fadd_rn(a.y, e4.y), 3.0f);
        f.z = __fdiv_rn(__fadd_rn(a.z, e4.z), 3.0f);
        f.w = __fdiv_rn(__fadd_rn(a.w, e4.w), 3.0f);
        ntstore4(accF + idx, f);
    }
}

extern "C" void kernel_launch(void* const* d_in, const int* in_sizes, int n_in,
                              void* d_out, int out_size, void* d_ws, size_t ws_size,
                              hipStream_t stream) {
    if (ws_size < WS_NEED) return;

    const float* user_emb = (const float*)d_in[0];
    const float* item_emb = (const float*)d_in[1];
    const int*   adj_rows = (const int*)d_in[2];
    const int*   adj_cols = (const int*)d_in[3];
    const float* adj_vals = (const float*)d_in[4];
    const float* noise    = (const float*)d_in[5];

    char* ws = (char*)d_ws;
    float* bufB = (float*)(ws + BUFB_OFF);
    int*   keys = (int*)(ws + BUFA_OFF);    // build scratch (bufA unused since R10)
    int2*  zip  = (int2*)(ws + BUFB_OFF);   // aliased: dead before bufB first write
    int*   bcnt_part = (int*)(ws + CV_OFF); // aliased: dead before cv written
    int2*  cv   = (int2*)(ws + CV_OFF);
    int*   rs   = (int*)(ws + RS_OFF);
    int*   bcnt = (int*)(ws + SMALL_OFF);
    int*   bbase= (int*)(ws + SMALL_OFF + 3200);
    int*   gcur = (int*)(ws + SMALL_OFF + 6400);

    float* accF = (float*)d_out;
    float* clF  = (float*)d_out + (size_t)N_NODES * EMB;

    // ---- CSR build (keys/zip/bcnt_part alias ws regions: all consumed
    //      before their aliases are written; single stream) ----
    k_prep<<<NBLK, TB_A, 0, stream>>>(adj_rows, adj_cols, adj_vals, bcnt_part,
                                      zip);
    k_scan782<<<1, 1024, 0, stream>>>(bcnt_part, bcnt, bbase, gcur, rs);
    k_bin<<<NBLK, TB_A, 0, stream>>>(adj_rows, gcur, keys);
    k_build<<<NBUCK, 256, 0, stream>>>(keys, zip, bcnt, bbase, cv, rs);

    // ---- 3 layers: fused norm+spmm+epilogue ----
    // L0: gather user/item -> write clF. L1: gather clF -> write bufB.
    // L2: gather bufB -> write accF (acc recomputed from clF + bufB).
    const int T16 = N_NODES * 16;
    for (int k = 0; k < 3; ++k) {
        const float* nkp = noise + (size_t)k * N_NODES * EMB;
        const float* xlo  = (k == 0) ? user_emb : ((k == 1) ? clF : bufB);
        const float* xhi  = (k == 0) ? item_emb : ((k == 1) ? clF : bufB);
        int split = (k == 0) ? USER_NUM : 0;
        k_fused<<<T16 / 256, 256, 0, stream>>>(rs, cv, xlo, xhi, split,
                                               nkp, bufB, accF, clF, k);
    }
}

// Round 12
// 1207.350 us; speedup vs baseline: 1.1017x; 1.0026x over previous
//
#include <hip/hip_runtime.h>

// GCLSDA encoder: ego=concat(U,I); 3x { ego = A@ego; ego += sign(ego)*nhat*0.1; acc+=ego }
// Outputs: final=acc/3, cl=ego_layer1.
// Numerics: SpMM accumulates per (row,dim) sequentially in ascending edge-index
// order with separate _rn mul/add (matches np.add.at); norm uses numpy
// pairwise-sum 8-accumulator pattern (fused in-wave since R9). Exact order is
// LOAD-BEARING: sign(ego) amplifies ~1e-7 reorder noise into ~1e-2 errors at
// near-zero ego elements. Do NOT reorder accumulation or the norm fold.
//
// R12: build-chain consolidation. R11 accounting: fused 751 + build 150 +
// {prep,scan,bin} ~310 incl ~25us/launch boundaries. k_bin's phase-1
// histogram == bcnt_part[blockIdx] (already in memory from k_prep), and the
// gcur atomics + k_scan782 are replaced by a per-block SELF-SCAN of the
// 1.22MB partials table (L2-resident, coalesced): each block derives global
// bucket bases AND its deterministic cross-block prefix. k_bin loses a full
// 25.6MB rows pass + 6.4M LDS atomics; k_scan782 deleted (k_bin block 0
// writes bcnt/bbase/rs[N] — all blocks compute identical values). Launches
// 7->6. Intra-bucket bins order changes only within its already-arbitrary
// permutation — k_build's rank-by-key makes cv bit-identical.
// R11 (verified): nt ONLY on single-touch streams (nk, mode2 clF read,
// output stores); cv loads cached (8 entries/line reuse — R10 lesson).
// R10 (verified): mode0 single store (layer 1 gathers from clF); acc
// deferred to mode2 (a=fadd(clF,bufB) == ((cl+e1)+e2), bit-identical).
// R9: norm fused in-wave (7-step shfl_up ring, exact numpy order).
// R8 REVERTED (dim-split: random gathers see per-XCD 4MB L2).
// R7: zip gather. R6: keys-only binning. R3/R4: epilogue fused into spmm;
// layer-0 virtual concat; dead stores dropped.
//
// CSR build: bucket = row>>8 (782 buckets). A1 prep (partial counts + zip) ->
// A2 bin {self-scan + scatter keys} -> B per-bucket rank-scatter (keys unique
// ((rl<<24)|e): final slot = start[rl] + #{same-row keys < mine}; each cv
// written ONCE). KEY RECOVERY MUST BE LOGICAL SHIFT: (unsigned)key>>24.
// e = key & 0xFFFFFF.
// Aliasing timeline: bcnt_part@CV (consumed by k_bin before k_build writes
// cv); keys@bufA (build scratch only); zip@bufB (dead before layer-1 write).

#define USER_NUM 100000
#define N_NODES  200000
#define EMB      64
#define N_EDGES  6400000
#define NBUCK    782        // ceil(200000/256)
#define CAP      9216       // max edges/bucket on LDS fast path (mu=8184, +11 sigma)
#define EPB      16384      // edges per block in A1/A2
#define TB_A     1024       // threads per block in A1/A2
#define NBLK     391        // ceil(N_EDGES/EPB)

static constexpr size_t BUFA_OFF  = 0;
static constexpr size_t BUFB_OFF  = 51200000;
static constexpr size_t CV_OFF    = 102400000;
static constexpr size_t RS_OFF    = 153600000;
static constexpr size_t SMALL_OFF = 154400016;
static constexpr size_t WS_NEED   = 156000016;

// ---- non-temporal (evict-first) load/store helpers — SINGLE-TOUCH streams
// only (nk, mode2 clF read, output stores). NOT cv (line reuse, R10 lesson).
typedef float f4v __attribute__((ext_vector_type(4)));

__device__ __forceinline__ float4 ntload4(const float* p) {
    f4v v = __builtin_nontemporal_load((const f4v*)p);
    return make_float4(v.x, v.y, v.z, v.w);
}
__device__ __forceinline__ void ntstore4(float* p, float4 v) {
    f4v t = {v.x, v.y, v.z, v.w};
    __builtin_nontemporal_store(t, (f4v*)p);
}

// ---- Pass A1: per-block bucket counts (no atomics/memset) + zip write ----
__global__ __launch_bounds__(TB_A) void k_prep(const int* __restrict__ rows,
                                               const int* __restrict__ cols,
                                               const float* __restrict__ vals,
                                               int* __restrict__ bcnt_part,
                                               int2* __restrict__ zip) {
    __shared__ int h[NBUCK];
    for (int i = threadIdx.x; i < NBUCK; i += TB_A) h[i] = 0;
    __syncthreads();
    int base = blockIdx.x * EPB;
    int end  = min(base + EPB, N_EDGES);
    for (int e = base + threadIdx.x; e < end; e += TB_A) {
        atomicAdd(&h[rows[e] >> 8], 1);
        zip[e] = make_int2(cols[e], __float_as_int(vals[e]));
    }
    __syncthreads();
    for (int i = threadIdx.x; i < NBUCK; i += TB_A)
        bcnt_part[blockIdx.x * NBUCK + i] = h[i];
}

// ---- Pass A2: self-scan partials -> bases; scatter edge KEYS into bucket
// regions. Each block reads the full partials table (1.22MB, L2-resident,
// coalesced across tid at each b) computing: tot[i] (global bucket count),
// pre[i] (sum of partials from blocks < blk — deterministic cross-block
// prefix), then an LDS exclusive scan of tot -> global bucket base. Block's
// write base gb[i] = bbase[i] + pre[i]; local rank via fresh LDS atomic.
// Intra-bucket order is arbitrary (k_build sorts by key). Block 0 persists
// bcnt/bbase (identical values in all blocks) and rs[N]=E. ----
__global__ __launch_bounds__(TB_A) void k_bin(const int* __restrict__ rows,
                                              const int* __restrict__ bcnt_part,
                                              int* __restrict__ bcnt,
                                              int* __restrict__ bbase,
                                              int* __restrict__ rs,
                                              int* __restrict__ keys) {
    __shared__ int gb[NBUCK];
    __shared__ int h[NBUCK];
    __shared__ int s[1024];
    int tid = threadIdx.x;
    int blk = blockIdx.x;
    int tot = 0, pre = 0;
    if (tid < NBUCK) {
        for (int b = 0; b < NBLK; ++b) {
            int v = bcnt_part[b * NBUCK + tid];
            tot += v;
            if (b < blk) pre += v;
        }
    }
    s[tid] = (tid < NBUCK) ? tot : 0;
    __syncthreads();
    for (int off = 1; off < 1024; off <<= 1) {
        int t = 0;
        if (tid >= off) t = s[tid - off];
        __syncthreads();
        s[tid] += t;
        __syncthreads();
    }
    if (tid < NBUCK) {
        int ex = s[tid] - tot;          // exclusive scan = global bucket base
        gb[tid] = ex + pre;             // this block's write base
        h[tid] = 0;
        if (blk == 0) {
            bcnt[tid] = tot;
            bbase[tid] = ex;
        }
    }
    if (blk == 0 && tid == 0) rs[N_NODES] = N_EDGES;
    __syncthreads();
    int base = blk * EPB;
    int end  = min(base + EPB, N_EDGES);
    for (int e = base + tid; e < end; e += TB_A) {
        int r = rows[e];
        int b = r >> 8;
        int pos = gb[b] + atomicAdd(&h[b], 1);
        keys[pos] = ((r & 255) << 24) | e;  // e < 2^23, row-local in top byte
    }
}

// ---- Pass B: per-bucket row-grouping + stable (edge-idx) ordering -> cv, rs.
// (col,val) gathered from zip via e = key & 0xFFFFFF: ONE 64B line per edge. ----
__global__ __launch_bounds__(256) void k_build(const int* __restrict__ keys,
                                               const int2* __restrict__ zip,
                                               const int* __restrict__ bcnt,
                                               const int* __restrict__ bbase,
                                               int2* __restrict__ cv,
                                               int* __restrict__ rs) {
    __shared__ int cnt[256];
    __shared__ int start[256];
    __shared__ int cur[256];
    __shared__ int scanbuf[256];
    __shared__ int eKey[CAP];     // grouped keys (fast path)
    int tid = threadIdx.x;
    int b = blockIdx.x;
    int n = bcnt[b];
    int base = bbase[b];
    int rowbase = b << 8;
    cnt[tid] = 0;
    __syncthreads();
    // step 1: per-row-local histogram (LOGICAL shift: rl in [0,255])
    for (int i = tid; i < n; i += 256) {
        unsigned key = (unsigned)keys[base + i];
        atomicAdd(&cnt[key >> 24], 1);
    }
    __syncthreads();
    // exclusive scan of cnt -> start
    int v = cnt[tid];
    scanbuf[tid] = v;
    __syncthreads();
    for (int off = 1; off < 256; off <<= 1) {
        int t = 0;
        if (tid >= off) t = scanbuf[tid - off];
        __syncthreads();
        scanbuf[tid] += t;
        __syncthreads();
    }
    start[tid] = scanbuf[tid] - v;
    {
        int row = rowbase + tid;
        if (row < N_NODES) rs[row] = base + start[tid];
    }
    cur[tid] = 0;
    __syncthreads();
    if (n <= CAP) {
        // step 2: group keys by row into LDS (intra-row order arbitrary here)
        for (int i = tid; i < n; i += 256) {
            int key = keys[base + i];                   // L2-hot re-read
            int rl = (int)((unsigned)key >> 24);
            int p = start[rl] + atomicAdd(&cur[rl], 1);
            eKey[p] = key;
        }
        __syncthreads();
        // step 3: rank = #{same-row keys < mine} -> final slot; write cv ONCE.
        // Keys unique => bijection; same top byte within a row => signed cmp
        // orders by edge idx. (col,val) gathered from zip in one line.
        for (int p = tid; p < n; p += 256) {
            int k = eKey[p];
            int rl = (int)((unsigned)k >> 24);
            int s0 = start[rl];
            int s1 = s0 + cnt[rl];
            int rank = 0;
            int q = s0;
            for (; q + 4 <= s1; q += 4) {
                rank += (eKey[q]     < k);
                rank += (eKey[q + 1] < k);
                rank += (eKey[q + 2] < k);
                rank += (eKey[q + 3] < k);
            }
            for (; q < s1; ++q) rank += (eKey[q] < k);
            int e = k & 0x00FFFFFF;
            cv[base + s0 + rank] = zip[e];
        }
    } else {
        // overflow fallback (statistically unreachable, +11 sigma):
        // scatter keys into cv[].x, per-row insertion sort by key (global,
        // slow but correct), then rewrite each slot from zip via e.
        for (int i = tid; i < n; i += 256) {
            int key = keys[base + i];
            int rl = (int)((unsigned)key >> 24);
            int p = start[rl] + atomicAdd(&cur[rl], 1);
            cv[base + p] = make_int2(key, 0);
        }
        __syncthreads();
        int c = cnt[tid];
        if (c > 1) {
            int s0 = start[tid];
            int s1 = s0 + c;
            for (int i = s0 + 1; i < s1; ++i) {
                int2 kv = cv[base + i];
                int j = i - 1;
                while (j >= s0 && cv[base + j].x > kv.x) {
                    cv[base + j + 1] = cv[base + j];
                    --j;
                }
                cv[base + j + 1] = kv;
            }
        }
        __syncthreads();
        // each slot read exactly once by its own thread, then overwritten
        for (int i = tid; i < n; i += 256) {
            int e = cv[base + i].x & 0x00FFFFFF;
            cv[base + i] = zip[e];
        }
    }
}

// ---- Fused SpMM + norm + epilogue. One thread per (row, 4-dim group); a
// row's 16 threads form one 16-lane wave segment. Row norm computed in-wave
// (exact numpy pairwise order): lane u holds dims 4u..4u+3; chains rj[0..3]
// are left-folds over even lanes, rj[4..7] over odd lanes, both in increasing
// lane order -> 7-step serial __shfl_up(.,2,16) ring; lane14 ends with
// r0..r3, lane15 with r4..r7; tAB = fadd(fadd(f0,f1),fadd(f2,f3)) gives
// s01+s23 (lane14) and s45+s67 (lane15); ss = fadd(lane14,lane15).
// 3-edge pipelined gather groups. x gather AND cv loads are CACHED (cv has
// line reuse — R10 lesson); nk is nt (single-touch). x base select {base,
// rebased col} in-kernel: layer 0 reads user/item directly (split=100000);
// layer 1 gathers from clF; layer 2 from bufB.
// Epilogue: e4 = y + sign(y)*nk/nv*0.1;
//   mode0: clF=e4                    (ego dropped — layer 1 reads clF)
//   mode1: ego=e4                    (acc deferred — e4 IS layer-2's x)
//   mode2: a=fadd(clF,x[idx]); accF=fdiv(fadd(a,e4),3)
//     (a == old mode1's accF=clF+e4_l1 bit-exactly: x[idx]=bufB[idx]=e4_l1)
// NOTE: grid exactly covers N_NODES*16 threads — no lane early-exits, so the
// shfl ring sees all 16 lanes of every segment.
__global__ __launch_bounds__(256) void k_fused(const int* __restrict__ rs,
                                               const int2* __restrict__ cv,
                                               const float* __restrict__ xlo,
                                               const float* __restrict__ xhi,
                                               int split,
                                               const float* __restrict__ nk,
                                               float* __restrict__ ego,
                                               float* __restrict__ accF,
                                               float* __restrict__ clF,
                                               int mode) {
    int t = blockIdx.x * blockDim.x + threadIdx.x;
    int r = t >> 4;
    int u = t & 15;
    int c = u << 2;
    int idx = t << 2;                       // == r*EMB + c
    // ---- in-wave row norm (exact numpy pairwise order) ----
    float4 n4 = ntload4(nk + idx);
    float q0 = __fmul_rn(n4.x, n4.x);
    float q1 = __fmul_rn(n4.y, n4.y);
    float q2 = __fmul_rn(n4.z, n4.z);
    float q3 = __fmul_rn(n4.w, n4.w);
    float f0 = q0, f1 = q1, f2 = q2, f3 = q3;
    #pragma unroll
    for (int s = 0; s < 7; ++s) {
        float g0 = __shfl_up(f0, 2, 16);
        float g1 = __shfl_up(f1, 2, 16);
        float g2 = __shfl_up(f2, 2, 16);
        float g3 = __shfl_up(f3, 2, 16);
        if (u >= 2) {
            f0 = __fadd_rn(g0, q0);
            f1 = __fadd_rn(g1, q1);
            f2 = __fadd_rn(g2, q2);
            f3 = __fadd_rn(g3, q3);
        }
    }
    float tAB = __fadd_rn(__fadd_rn(f0, f1), __fadd_rn(f2, f3));
    float tlo = __shfl(tAB, 14, 16);        // s01+s23 (chains from even lanes)
    float thi = __shfl(tAB, 15, 16);        // s45+s67 (chains from odd lanes)
    float nv = __fsqrt_rn(__fadd_rn(tlo, thi));
    nv = fmaxf(nv, 1e-12f);
    // ---- SpMM ----
    int j0 = rs[r], j1 = rs[r + 1];
    float a0 = 0.f, a1 = 0.f, a2 = 0.f, a3 = 0.f;
    if (j0 < j1) {
        const int EMAX = N_EDGES - 1;
        // two-base gather: base and rebased column selected together
        #define XROW(col) (((col) < split ? xlo : xhi) + \
                           ((col) < split ? (col) : (col) - split) * EMB + c)
        int2 c0 = cv[j0];
        int2 c1 = cv[min(j0 + 1, EMAX)];
        int2 c2 = cv[min(j0 + 2, EMAX)];
        int2 n0 = cv[min(j0 + 3, EMAX)];
        int2 n1 = cv[min(j0 + 4, EMAX)];
        int2 n2 = cv[min(j0 + 5, EMAX)];
        int2 m0 = cv[min(j0 + 6, EMAX)];
        int2 m1 = cv[min(j0 + 7, EMAX)];
        int2 m2 = cv[min(j0 + 8, EMAX)];
        float4 x0 = *(const float4*)XROW(c0.x);
        float4 x1 = *(const float4*)XROW(c1.x);
        float4 x2 = *(const float4*)XROW(c2.x);
        for (int j = j0; j < j1; j += 3) {
            // x prefetch for next group (cv loaded 2 iterations ago)
            float4 y0 = *(const float4*)XROW(n0.x);
            float4 y1 = *(const float4*)XROW(n1.x);
            float4 y2 = *(const float4*)XROW(n2.x);
            // accumulate current group (predicate out-of-row edges to v=0;
            // a + (+/-0) is exact, so active-edge order/values unchanged)
            float v0 = __int_as_float(c0.y);
            float v1 = (j + 1 < j1) ? __int_as_float(c1.y) : 0.f;
            float v2 = (j + 2 < j1) ? __int_as_float(c2.y) : 0.f;
            a0 = __fadd_rn(a0, __fmul_rn(v0, x0.x));
            a1 = __fadd_rn(a1, __fmul_rn(v0, x0.y));
            a2 = __fadd_rn(a2, __fmul_rn(v0, x0.z));
            a3 = __fadd_rn(a3, __fmul_rn(v0, x0.w));
            a0 = __fadd_rn(a0, __fmul_rn(v1, x1.x));
            a1 = __fadd_rn(a1, __fmul_rn(v1, x1.y));
            a2 = __fadd_rn(a2, __fmul_rn(v1, x1.z));
            a3 = __fadd_rn(a3, __fmul_rn(v1, x1.w));
            a0 = __fadd_rn(a0, __fmul_rn(v2, x2.x));
            a1 = __fadd_rn(a1, __fmul_rn(v2, x2.y));
            a2 = __fadd_rn(a2, __fmul_rn(v2, x2.z));
            a3 = __fadd_rn(a3, __fmul_rn(v2, x2.w));
            // rotate pipeline
            c0 = n0; c1 = n1; c2 = n2;
            n0 = m0; n1 = m1; n2 = m2;
            x0 = y0; x1 = y1; x2 = y2;
            // streaming cv prefetch, 2 groups ahead of its x-gather
            m0 = cv[min(j + 9,  EMAX)];
            m1 = cv[min(j + 10, EMAX)];
            m2 = cv[min(j + 11, EMAX)];
        }
        #undef XROW
    }
    // ---- fused epilogue (identical math/order to the original k_epi) ----
    float4 e4;
    {
        float s, q;
        s = (a0 > 0.f) ? 1.f : ((a0 < 0.f) ? -1.f : 0.f);
        q = __fdiv_rn(n4.x, nv);
        e4.x = __fadd_rn(a0, __fmul_rn(__fmul_rn(s, q), 0.1f));
        s = (a1 > 0.f) ? 1.f : ((a1 < 0.f) ? -1.f : 0.f);
        q = __fdiv_rn(n4.y, nv);
        e4.y = __fadd_rn(a1, __fmul_rn(__fmul_rn(s, q), 0.1f));
        s = (a2 > 0.f) ? 1.f : ((a2 < 0.f) ? -1.f : 0.f);
        q = __fdiv_rn(n4.z, nv);
        e4.z = __fadd_rn(a2, __fmul_rn(__fmul_rn(s, q), 0.1f));
        s = (a3 > 0.f) ? 1.f : ((a3 < 0.f) ? -1.f : 0.f);
        q = __fdiv_rn(n4.w, nv);
        e4.w = __fadd_rn(a3, __fmul_rn(__fmul_rn(s, q), 0.1f));
    }
    if (mode == 0) {
        ntstore4(clF + idx, e4);
    } else if (mode == 1) {
        ntstore4(ego + idx, e4);
    } else {
        float4 cl4 = ntload4(clF + idx);
        float4 x1 = *(const float4*)(xhi + idx);  // bufB = layer-1 e4 (cached:
        float4 a;                                 // it's this layer's x too)
        a.x = __fadd_rn(cl4.x, x1.x);
        a.y = __fadd_rn(cl4.y, x1.y);
        a.z = __fadd_rn(cl4.z, x1.z);
        a.w = __fadd_rn(cl4.w, x1.w);
        float4 f;
        f.x = __fdiv_rn(__fadd_rn(a.x, e4.x), 3.0f);
        f.y = __fdiv_rn(__fadd_rn(a.y, e4.y), 3.0f);
        f.z = __fdiv_rn(__fadd_rn(a.z, e4.z), 3.0f);
        f.w = __fdiv_rn(__fadd_rn(a.w, e4.w), 3.0f);
        ntstore4(accF + idx, f);
    }
}

extern "C" void kernel_launch(void* const* d_in, const int* in_sizes, int n_in,
                              void* d_out, int out_size, void* d_ws, size_t ws_size,
                              hipStream_t stream) {
    if (ws_size < WS_NEED) return;

    const float* user_emb = (const float*)d_in[0];
    const float* item_emb = (const float*)d_in[1];
    const int*   adj_rows = (const int*)d_in[2];
    const int*   adj_cols = (const int*)d_in[3];
    const float* adj_vals = (const float*)d_in[4];
    const float* noise    = (const float*)d_in[5];

    char* ws = (char*)d_ws;
    float* bufB = (float*)(ws + BUFB_OFF);
    int*   keys = (int*)(ws + BUFA_OFF);    // build scratch (bufA unused as ego)
    int2*  zip  = (int2*)(ws + BUFB_OFF);   // aliased: dead before bufB first write
    int*   bcnt_part = (int*)(ws + CV_OFF); // aliased: dead before cv written
    int2*  cv   = (int2*)(ws + CV_OFF);
    int*   rs   = (int*)(ws + RS_OFF);
    int*   bcnt = (int*)(ws + SMALL_OFF);
    int*   bbase= (int*)(ws + SMALL_OFF + 3200);

    float* accF = (float*)d_out;
    float* clF  = (float*)d_out + (size_t)N_NODES * EMB;

    // ---- CSR build (keys/zip/bcnt_part alias ws regions: all consumed
    //      before their aliases are written; single stream) ----
    k_prep<<<NBLK, TB_A, 0, stream>>>(adj_rows, adj_cols, adj_vals, bcnt_part,
                                      zip);
    k_bin<<<NBLK, TB_A, 0, stream>>>(adj_rows, bcnt_part, bcnt, bbase, rs,
                                     keys);
    k_build<<<NBUCK, 256, 0, stream>>>(keys, zip, bcnt, bbase, cv, rs);

    // ---- 3 layers: fused norm+spmm+epilogue ----
    // L0: gather user/item -> write clF. L1: gather clF -> write bufB.
    // L2: gather bufB -> write accF (acc recomputed from clF + bufB).
    const int T16 = N_NODES * 16;
    for (int k = 0; k < 3; ++k) {
        const float* nkp = noise + (size_t)k * N_NODES * EMB;
        const float* xlo  = (k == 0) ? user_emb : ((k == 1) ? clF : bufB);
        const float* xhi  = (k == 0) ? item_emb : ((k == 1) ? clF : bufB);
        int split = (k == 0) ? USER_NUM : 0;
        k_fused<<<T16 / 256, 256, 0, stream>>>(rs, cv, xlo, xhi, split,
                                               nkp, bufB, accF, clF, k);
    }
}